// Round 1
// baseline (1516.437 us; speedup 1.0000x reference)
//
#include <hip/hip_runtime.h>
#include <hip/hip_bf16.h>
#include <math.h>

// Problem constants
#define N_ROWS 16384      // 8 * 2048
#define DIM    256
#define KCODES 8192

// Output layout (float offsets), reference return order:
// z_q_st (16384*256), codes (16384), vq_loss (1),
// new_codebook (8192*256), new_cluster_size (8192), new_ema_w (8192*256)
#define OFF_ZQ    0
#define OFF_CODES 4194304
#define OFF_LOSS  4210688
#define OFF_CB    4210689
#define OFF_CS    6307841
#define OFF_EW    6316033
#define OUT_TOTAL 8413185

// ---------------- K0: codebook row norms ||c||^2 -> cnorm[8192] ----------
__global__ __launch_bounds__(64) void k_cnorm(const float* __restrict__ cb,
                                              float* __restrict__ cnorm) {
  const int j = blockIdx.x;
  const int t = threadIdx.x;
  const float4 v = *(const float4*)(cb + ((size_t)j << 8) + (t << 2));
  float s = v.x * v.x + v.y * v.y + v.z * v.z + v.w * v.w;
#pragma unroll
  for (int off = 32; off >= 1; off >>= 1) s += __shfl_down(s, off);
  if (t == 0) cnorm[j] = s;
}

// ---------------- K1: argmin over codes (dist' = ||c||^2 - 2 z.c) --------
// 256 threads, 64 rows/block, 8x8 register blocking, codes chunked 256x64.
__global__ __launch_bounds__(256, 1) void k_argmin(
    const float* __restrict__ z, const float* __restrict__ cb,
    const float* __restrict__ cnorm, float* __restrict__ out_codes) {
  __shared__ float  zs[64][260];       // 64 rows x 256 dims (+pad), 66.5 KB
  __shared__ float4 cs4[256 * 16];     // 256 codes x 64 dims, XOR-swizzled, 64 KB

  const int tid = threadIdx.x;
  const int tx = tid & 31;             // code group (8 codes each)
  const int ty = tid >> 5;             // row group (8 rows each)
  const int row0 = blockIdx.x << 6;

  // stage z tile (coalesced float4)
#pragma unroll
  for (int it = 0; it < 16; ++it) {
    int idx = tid + (it << 8);
    int r = idx >> 6, dq = idx & 63;
    float4 v = *(const float4*)(z + (((size_t)(row0 + r)) << 8) + (dq << 2));
    *(float4*)&zs[r][dq << 2] = v;
  }

  float b1[8], b2[8];
  int   j1[8], j2[8];
#pragma unroll
  for (int i = 0; i < 8; ++i) {
    b1[i] = 3.4e38f; b2[i] = 3.4e38f; j1[i] = 0x7fffffff; j2[i] = 0x7fffffff;
  }

  for (int ch = 0; ch < KCODES / 256; ++ch) {
    float acc[8][8];
#pragma unroll
    for (int i = 0; i < 8; ++i)
#pragma unroll
      for (int j = 0; j < 8; ++j) acc[i][j] = 0.0f;

    for (int dsb = 0; dsb < 4; ++dsb) {
      __syncthreads();  // previous chunk readers done before overwrite
      // stage 256 codes x 64 dims, slot-swizzled: phys = c ^ ((r>>3)&15)
#pragma unroll
      for (int it = 0; it < 16; ++it) {
        int idx = tid + (it << 8);
        int r = idx >> 4, c = idx & 15;
        float4 v = *(const float4*)(cb + (((size_t)((ch << 8) + r)) << 8) +
                                    (dsb << 6) + (c << 2));
        cs4[(r << 4) | (c ^ ((r >> 3) & 15))] = v;
      }
      __syncthreads();

#pragma unroll 2
      for (int d4 = 0; d4 < 16; ++d4) {
        float4 zv[8], cv[8];
        const int dbase = (dsb << 6) | (d4 << 2);
#pragma unroll
        for (int i = 0; i < 8; ++i)
          zv[i] = *(const float4*)&zs[(ty << 3) + i][dbase];
#pragma unroll
        for (int j = 0; j < 8; ++j)
          cv[j] = cs4[((((tx << 3) + j)) << 4) | (d4 ^ (tx & 15))];
#pragma unroll
        for (int j = 0; j < 8; ++j)
#pragma unroll
          for (int i = 0; i < 8; ++i) {
            acc[i][j] += zv[i].x * cv[j].x;
            acc[i][j] += zv[i].y * cv[j].y;
            acc[i][j] += zv[i].z * cv[j].z;
            acc[i][j] += zv[i].w * cv[j].w;
          }
      }
    }

    // fold into best/second-best (codes strictly increasing per thread)
#pragma unroll
    for (int j = 0; j < 8; ++j) {
      const int code = (ch << 8) + (tx << 3) + j;
      const float cn = cnorm[code];
#pragma unroll
      for (int i = 0; i < 8; ++i) {
        float m = cn - 2.0f * acc[i][j];
        if (m < b1[i]) { b2[i] = b1[i]; j2[i] = j1[i]; b1[i] = m; j1[i] = code; }
        else if (m < b2[i]) { b2[i] = m; j2[i] = code; }
      }
    }
  }

  // cross-thread reduction: reuse cs4 as scratch
  __syncthreads();
  float* rB1 = (float*)cs4;
  int*   rJ1 = (int*)(rB1 + 2048);
  float* rB2 = rB1 + 4096;
  int*   rJ2 = (int*)(rB1 + 6144);
#pragma unroll
  for (int i = 0; i < 8; ++i) {
    int r = (ty << 3) + i;
    rB1[(r << 5) + tx] = b1[i]; rJ1[(r << 5) + tx] = j1[i];
    rB2[(r << 5) + tx] = b2[i]; rJ2[(r << 5) + tx] = j2[i];
  }
  __syncthreads();

  if (tid < 64) {
    const int r = tid;
    float B1 = 3.4e38f, B2 = 3.4e38f;
    int   J1 = 0x7fffffff, J2 = 0x7fffffff;
    for (int t = 0; t < 32; ++t) {
      float m = rB1[(r << 5) + t]; int j = rJ1[(r << 5) + t];
      if (m < B1 || (m == B1 && j < J1)) { B2 = B1; J2 = J1; B1 = m; J1 = j; }
      else if (m < B2 || (m == B2 && j < J2)) { B2 = m; J2 = j; }
      m = rB2[(r << 5) + t]; j = rJ2[(r << 5) + t];
      if (m < B1 || (m == B1 && j < J1)) { B2 = B1; J2 = J1; B1 = m; J1 = j; }
      else if (m < B2 || (m == B2 && j < J2)) { B2 = m; J2 = j; }
    }
    int chosen = J1;
    // near-tie: resolve exactly in fp64 (protects argmin vs reference rounding)
    if (J2 != 0x7fffffff && (B2 - B1) < 4.0e-3f) {
      const float* c1 = cb + ((size_t)J1 << 8);
      const float* c2 = cb + ((size_t)J2 << 8);
      double d1 = 0.0, d2 = 0.0;
      for (int d = 0; d < DIM; ++d) {
        double zd = (double)zs[r][d];
        double e1 = zd - (double)c1[d]; d1 += e1 * e1;
        double e2 = zd - (double)c2[d]; d2 += e2 * e2;
      }
      if (d2 < d1 || (d2 == d1 && J2 < J1)) chosen = J2;
    }
    out_codes[row0 + r] = (float)chosen;
  }
}

// ---------------- K2: gather z_q, loss reduce, segment sums --------------
__global__ __launch_bounds__(256) void k_scatter(
    const float* __restrict__ z, const float* __restrict__ cb,
    const float* __restrict__ codesf, float* __restrict__ zq,
    float* __restrict__ loss, float* __restrict__ cs_acc,
    float* __restrict__ ew_acc) {
  const int row = blockIdx.x;
  const int d = threadIdx.x;
  const int c = (int)codesf[row];
  const float zv = z[((size_t)row << 8) + d];
  const float qv = cb[((size_t)c << 8) + d];
  zq[((size_t)row << 8) + d] = zv + (qv - zv);  // straight-through value
  float diff = zv - qv;
  float sq = diff * diff;
#pragma unroll
  for (int off = 32; off >= 1; off >>= 1) sq += __shfl_down(sq, off);
  __shared__ float wpart[4];
  if ((d & 63) == 0) wpart[d >> 6] = sq;
  __syncthreads();
  if (d == 0) {
    float s = (wpart[0] + wpart[1]) + (wpart[2] + wpart[3]);
    atomicAdd(loss, s * (float)(0.1 / 4194304.0));  // BETA * mean
    atomicAdd(cs_acc + c, 1.0f);                    // raw counts
  }
  atomicAdd(ew_acc + ((size_t)c << 8) + d, zv);     // raw dw sums
}

// ---------------- K3: EMA combine ----------------------------------------
__global__ __launch_bounds__(256) void k_ema_cs(const float* __restrict__ ema_cs,
                                                float* __restrict__ cs_io) {
  const int k = blockIdx.x * 256 + threadIdx.x;
  const float cnt = cs_io[k];
  cs_io[k] = 0.99f * ema_cs[k] + 0.01f * cnt;
}

__global__ __launch_bounds__(256) void k_ema_w(const float* __restrict__ ema_w,
                                               const float* __restrict__ cs_new,
                                               float* __restrict__ ew_io,
                                               float* __restrict__ cb_out) {
  const int i = blockIdx.x * 256 + threadIdx.x;
  const float dw = ew_io[i];
  const float v = 0.99f * ema_w[i] + 0.01f * dw;
  ew_io[i] = v;
  cb_out[i] = v / (cs_new[i >> 8] + 1e-5f);
}

// ---------------- launch --------------------------------------------------
extern "C" void kernel_launch(void* const* d_in, const int* in_sizes, int n_in,
                              void* d_out, int out_size, void* d_ws, size_t ws_size,
                              hipStream_t stream) {
  const float* z      = (const float*)d_in[0];
  const float* cb     = (const float*)d_in[1];
  const float* ema_cs = (const float*)d_in[2];
  const float* ema_w  = (const float*)d_in[3];
  float* out = (float*)d_out;

  float* o_zq    = out + OFF_ZQ;
  float* o_codes = out + OFF_CODES;
  float* o_loss  = out + OFF_LOSS;
  float* o_cb    = out + OFF_CB;   // also temp storage for cnorm before K3b
  float* o_cs    = out + OFF_CS;
  float* o_ew    = out + OFF_EW;

  // zero loss + cb(temp) + cs + ew regions (atomic accumulators need zeros
  // every call; harness does not re-poison between graph replays)
  hipMemsetAsync(o_loss, 0, (size_t)(OUT_TOTAL - OFF_LOSS) * sizeof(float), stream);

  k_cnorm <<<KCODES, 64, 0, stream>>>(cb, o_cb);
  k_argmin<<<N_ROWS / 64, 256, 0, stream>>>(z, cb, o_cb, o_codes);
  k_scatter<<<N_ROWS, 256, 0, stream>>>(z, cb, o_codes, o_zq, o_loss, o_cs, o_ew);
  k_ema_cs<<<KCODES / 256, 256, 0, stream>>>(ema_cs, o_cs);
  k_ema_w <<<KCODES * DIM / 256, 256, 0, stream>>>(ema_w, o_cs, o_ew, o_cb);
}

// Round 3
// 675.238 us; speedup vs baseline: 2.2458x; 2.2458x over previous
//
#include <hip/hip_runtime.h>
#include <hip/hip_bf16.h>
#include <math.h>

#define N_ROWS 16384      // 8 * 2048
#define DIM    256
#define KCODES 8192

// Output layout (float offsets), reference return order
#define OFF_ZQ    0
#define OFF_CODES 4194304
#define OFF_LOSS  4210688
#define OFF_CB    4210689
#define OFF_CS    6307841
#define OFF_EW    6316033
#define OUT_TOTAL 8413185

typedef __attribute__((ext_vector_type(8))) short bf16x8;
typedef __attribute__((ext_vector_type(4))) float f32x4;

__device__ __forceinline__ void gll16(const void* g, void* l) {
  __builtin_amdgcn_global_load_lds(
      (const __attribute__((address_space(1))) unsigned int*)g,
      (__attribute__((address_space(3))) unsigned int*)l, 16, 0, 0);
}

__device__ __forceinline__ unsigned short f2bf(float x) {
  __hip_bfloat16 h = __float2bfloat16(x);
  return *reinterpret_cast<unsigned short*>(&h);
}

// merge candidate (d, c) into ordered top-2 (b1,j1,b2,j2), tie -> lower index
#define MERGE1(d, c)                                                      \
  if ((d) < b1 || ((d) == b1 && (c) < j1)) {                              \
    b2 = b1; j2 = j1; b1 = (d); j1 = (c);                                 \
  } else if ((d) < b2 || ((d) == b2 && (c) < j2)) {                       \
    b2 = (d); j2 = (c);                                                   \
  }

// merge ordered pair (c1,i1,c2,i2) into (b1,j1,b2,j2)
#define MERGE2(c1, i1, c2, i2)                                            \
  if ((c1) < b1 || ((c1) == b1 && (i1) < j1)) {                           \
    float nb2; int nj2;                                                   \
    if (b1 < (c2) || (b1 == (c2) && j1 < (i2))) { nb2 = b1; nj2 = j1; }   \
    else { nb2 = (c2); nj2 = (i2); }                                      \
    b1 = (c1); j1 = (i1); b2 = nb2; j2 = nj2;                             \
  } else if ((c1) < b2 || ((c1) == b2 && (i1) < j2)) {                    \
    b2 = (c1); j2 = (i1);                                                 \
  }

// ---------------- fp32 -> bf16 convert (8 elems/thread) ------------------
__global__ __launch_bounds__(256) void k_cvt(const float* __restrict__ src,
                                             unsigned short* __restrict__ dst,
                                             int n8) {
  int i = blockIdx.x * 256 + threadIdx.x;
  if (i >= n8) return;
  const float4 a = ((const float4*)src)[i * 2];
  const float4 b = ((const float4*)src)[i * 2 + 1];
  union { unsigned short u[8]; uint4 v; } o;
  o.u[0] = f2bf(a.x); o.u[1] = f2bf(a.y); o.u[2] = f2bf(a.z); o.u[3] = f2bf(a.w);
  o.u[4] = f2bf(b.x); o.u[5] = f2bf(b.y); o.u[6] = f2bf(b.z); o.u[7] = f2bf(b.w);
  ((uint4*)dst)[i] = o.v;
}

// ---------------- codebook row norms (exact fp32) ------------------------
__global__ __launch_bounds__(64) void k_cnorm(const float* __restrict__ cb,
                                              float* __restrict__ cnorm) {
  const int j = blockIdx.x;
  const int t = threadIdx.x;
  const float4 v = *(const float4*)(cb + ((size_t)j << 8) + (t << 2));
  float s = v.x * v.x + v.y * v.y + v.z * v.z + v.w * v.w;
#pragma unroll
  for (int off = 32; off >= 1; off >>= 1) s += __shfl_down(s, off);
  if (t == 0) cnorm[j] = s;
}

// ---------------- MFMA distance + per-tile top-2 -------------------------
// grid (64 codetiles, 128 rowtiles), 256 threads (4 waves, 2x2 of 64x64)
__global__ __launch_bounds__(256) void k_argmin_mfma(
    const unsigned short* __restrict__ zb,   // [16384][256] bf16
    const unsigned short* __restrict__ cbb,  // [8192][256]  bf16
    const float* __restrict__ cnorm,         // [8192] fp32
    f32x4* __restrict__ partials) {          // [64][16384] {b1,j1,b2,j2}
  __shared__ __align__(16) unsigned char lds[32768];  // 2 x (8KB z + 8KB cb)

  const int tid = threadIdx.x;
  const int lane = tid & 63;
  const int w = tid >> 6;
  const int wm = w & 1, wn = w >> 1;
  const int ct = blockIdx.x;
  const int r0 = blockIdx.y << 7;
  const int c0 = ct << 7;

  // staging: slot s = issue*256+tid -> kq=s>>7, row=s&127; LDS = [kq][row][16B]
  const int srow = tid & 127;
  const int skq = tid >> 7;
  const char* zg = (const char*)zb + (size_t)(r0 + srow) * 512 + skq * 16;
  const char* cg = (const char*)cbb + (size_t)(c0 + srow) * 512 + skq * 16;

  // fragment LDS byte offsets (conflict-free linear layout)
  const int l4 = lane >> 4;    // k-quad
  const int lr = lane & 15;
  int aoff[4], boff[4];
#pragma unroll
  for (int i = 0; i < 4; ++i) {
    aoff[i] = l4 * 2048 + (wm * 64 + i * 16 + lr) * 16;
    boff[i] = l4 * 2048 + (wn * 64 + i * 16 + lr) * 16;
  }

  f32x4 acc[4][4];
#pragma unroll
  for (int i = 0; i < 4; ++i)
#pragma unroll
    for (int j = 0; j < 4; ++j) acc[i][j] = (f32x4)0.0f;

  // prologue stage ks=0 into buf0
  {
    unsigned char* lz = lds + tid * 16;
    unsigned char* lc = lds + 8192 + tid * 16;
    gll16(zg, lz);       gll16(zg + 32, lz + 4096);
    gll16(cg, lc);       gll16(cg + 32, lc + 4096);
  }

  int cur = 0;
  for (int ks = 0; ks < 8; ++ks) {
    __syncthreads();  // staging of buf[cur] complete (vmcnt drained per-thread)
    if (ks < 7) {
      const char* z1 = zg + (ks + 1) * 64;
      const char* c1 = cg + (ks + 1) * 64;
      unsigned char* lz = lds + (cur ^ 1) * 16384 + tid * 16;
      unsigned char* lc = lds + (cur ^ 1) * 16384 + 8192 + tid * 16;
      gll16(z1, lz);     gll16(z1 + 32, lz + 4096);
      gll16(c1, lc);     gll16(c1 + 32, lc + 4096);
    }
    const unsigned char* bz = lds + cur * 16384;
    const unsigned char* bc = bz + 8192;
    bf16x8 af[4], bfr[4];
#pragma unroll
    for (int i = 0; i < 4; ++i) af[i] = *(const bf16x8*)(bz + aoff[i]);
#pragma unroll
    for (int j = 0; j < 4; ++j) bfr[j] = *(const bf16x8*)(bc + boff[j]);
#pragma unroll
    for (int i = 0; i < 4; ++i)
#pragma unroll
      for (int j = 0; j < 4; ++j)
        acc[i][j] = __builtin_amdgcn_mfma_f32_16x16x32_bf16(af[i], bfr[j],
                                                            acc[i][j], 0, 0, 0);
    cur ^= 1;
  }

  // epilogue: b = cnorm - 2*dot ; per-row top-2 over this 128-code tile
  float cn[4];
#pragma unroll
  for (int j = 0; j < 4; ++j) cn[j] = cnorm[c0 + wn * 64 + j * 16 + lr];

  __syncthreads();                  // LDS buffers dead; reuse as scratch
  f32x4* scr = (f32x4*)lds;         // [2 codehalves][128 rows]

#pragma unroll
  for (int mi = 0; mi < 4; ++mi) {
#pragma unroll
    for (int r = 0; r < 4; ++r) {
      float b1 = 3.4e38f, b2 = 3.4e38f;
      int j1 = 0x7fffffff, j2 = 0x7fffffff;
#pragma unroll
      for (int nj = 0; nj < 4; ++nj) {
        float d = cn[nj] - 2.0f * acc[mi][nj][r];
        int c = c0 + wn * 64 + nj * 16 + lr;
        MERGE1(d, c);
      }
      // butterfly across the 16 code-columns (lane&15)
#pragma unroll
      for (int m = 1; m <= 8; m <<= 1) {
        float c1 = __shfl_xor(b1, m); int i1 = __shfl_xor(j1, m);
        float c2 = __shfl_xor(b2, m); int i2 = __shfl_xor(j2, m);
        MERGE2(c1, i1, c2, i2);
      }
      if (lr == 0) {
        int row_local = wm * 64 + mi * 16 + l4 * 4 + r;
        f32x4 e;
        e[0] = b1; e[1] = __int_as_float(j1);
        e[2] = b2; e[3] = __int_as_float(j2);
        scr[wn * 128 + row_local] = e;
      }
    }
  }
  __syncthreads();
  if (tid < 128) {
    f32x4 e0 = scr[tid], e1 = scr[128 + tid];
    float b1 = e0[0], b2 = e0[2];
    int j1 = __float_as_int(e0[1]), j2 = __float_as_int(e0[3]);
    float c1 = e1[0], c2 = e1[2];
    int i1 = __float_as_int(e1[1]), i2 = __float_as_int(e1[3]);
    MERGE2(c1, i1, c2, i2);
    f32x4 e;
    e[0] = b1; e[1] = __int_as_float(j1);
    e[2] = b2; e[3] = __int_as_float(j2);
    partials[(size_t)ct * 16384 + r0 + tid] = e;
  }
}

// ---------------- merge partials + exact refine ---------------------------
__global__ __launch_bounds__(128) void k_reduce(
    const f32x4* __restrict__ partials, const float* __restrict__ z,
    const float* __restrict__ cb, float* __restrict__ out_codes) {
  const int row = blockIdx.x * 128 + threadIdx.x;
  float b1 = 3.4e38f, b2 = 3.4e38f;
  int j1 = 0x7fffffff, j2 = 0x7fffffff;
  for (int ct = 0; ct < 64; ++ct) {
    f32x4 e = partials[(size_t)ct * 16384 + row];
    float c1 = e[0], c2 = e[2];
    int i1 = __float_as_int(e[1]), i2 = __float_as_int(e[3]);
    MERGE2(c1, i1, c2, i2);
  }
  int chosen = j1;
  if (b2 - b1 < 0.5f) {
    // bf16 ranking ambiguous: exact fp64 re-evaluation of every candidate
    // within the noise window (covers >5 sigma of bf16 dot error)
    const float* zr = z + ((size_t)row << 8);
    const float win = b1 + 0.5f;
    double bestd = 1e300; int bestj = 0x7fffffff;
    for (int ct = 0; ct < 64; ++ct) {
      f32x4 e = partials[(size_t)ct * 16384 + row];
#pragma unroll
      for (int h = 0; h < 2; ++h) {
        float bv = h ? e[2] : e[0];
        int jv = __float_as_int(h ? e[3] : e[1]);
        if (bv <= win && jv != 0x7fffffff) {
          const float* c = cb + ((size_t)jv << 8);
          double d = 0.0;
          for (int k = 0; k < DIM; ++k) {
            double df = (double)zr[k] - (double)c[k];
            d += df * df;
          }
          if (d < bestd || (d == bestd && jv < bestj)) { bestd = d; bestj = jv; }
        }
      }
    }
    chosen = bestj;
  }
  out_codes[row] = (float)chosen;
}

// ---------------- gather z_q, loss reduce, segment sums --------------
__global__ __launch_bounds__(256) void k_scatter(
    const float* __restrict__ z, const float* __restrict__ cb,
    const float* __restrict__ codesf, float* __restrict__ zq,
    float* __restrict__ loss, float* __restrict__ cs_acc,
    float* __restrict__ ew_acc) {
  const int row = blockIdx.x;
  const int d = threadIdx.x;
  const int c = (int)codesf[row];
  const float zv = z[((size_t)row << 8) + d];
  const float qv = cb[((size_t)c << 8) + d];
  zq[((size_t)row << 8) + d] = zv + (qv - zv);  // straight-through value
  float diff = zv - qv;
  float sq = diff * diff;
#pragma unroll
  for (int off = 32; off >= 1; off >>= 1) sq += __shfl_down(sq, off);
  __shared__ float wpart[4];
  if ((d & 63) == 0) wpart[d >> 6] = sq;
  __syncthreads();
  if (d == 0) {
    float s = (wpart[0] + wpart[1]) + (wpart[2] + wpart[3]);
    atomicAdd(loss, s * (float)(0.1 / 4194304.0));  // BETA * mean
    atomicAdd(cs_acc + c, 1.0f);
  }
  atomicAdd(ew_acc + ((size_t)c << 8) + d, zv);
}

// ---------------- EMA combine ----------------------------------------
__global__ __launch_bounds__(256) void k_ema_cs(const float* __restrict__ ema_cs,
                                                float* __restrict__ cs_io) {
  const int k = blockIdx.x * 256 + threadIdx.x;
  const float cnt = cs_io[k];
  cs_io[k] = 0.99f * ema_cs[k] + 0.01f * cnt;
}

__global__ __launch_bounds__(256) void k_ema_w(const float* __restrict__ ema_w,
                                               const float* __restrict__ cs_new,
                                               float* __restrict__ ew_io,
                                               float* __restrict__ cb_out) {
  const int i = blockIdx.x * 256 + threadIdx.x;
  const float dw = ew_io[i];
  const float v = 0.99f * ema_w[i] + 0.01f * dw;
  ew_io[i] = v;
  cb_out[i] = v / (cs_new[i >> 8] + 1e-5f);
}

// ---------------- launch --------------------------------------------------
extern "C" void kernel_launch(void* const* d_in, const int* in_sizes, int n_in,
                              void* d_out, int out_size, void* d_ws, size_t ws_size,
                              hipStream_t stream) {
  const float* z      = (const float*)d_in[0];
  const float* cb     = (const float*)d_in[1];
  const float* ema_cs = (const float*)d_in[2];
  const float* ema_w  = (const float*)d_in[3];
  float* out = (float*)d_out;

  float* o_zq    = out + OFF_ZQ;
  float* o_codes = out + OFF_CODES;
  float* o_loss  = out + OFF_LOSS;
  float* o_cb    = out + OFF_CB;
  float* o_cs    = out + OFF_CS;
  float* o_ew    = out + OFF_EW;

  // scratch aliases inside output regions (each later overwritten in order):
  //   z_bf16 (8 MB)   -> o_cb region (16B-aligned; <=12B spill into o_cs,
  //                      which is memset-zeroed before use)
  //   cb_bf16 (4 MB) + cnorm (32 KB) -> o_ew region
  //   partials (16.78 MB exact)      -> o_zq region
  uintptr_t zb_a  = ((uintptr_t)o_cb + 15) & ~(uintptr_t)15;
  uintptr_t cbb_a = ((uintptr_t)o_ew + 15) & ~(uintptr_t)15;
  unsigned short* zbuf  = (unsigned short*)zb_a;
  unsigned short* cbbuf = (unsigned short*)cbb_a;
  float* cnorm = (float*)(cbb_a + 4194304);
  f32x4* partials = (f32x4*)o_zq;

  k_cvt<<<2048, 256, 0, stream>>>(z, zbuf, 524288);
  k_cvt<<<1024, 256, 0, stream>>>(cb, cbbuf, 262144);
  k_cnorm<<<KCODES, 64, 0, stream>>>(cb, cnorm);

  dim3 g(64, 128);
  k_argmin_mfma<<<g, 256, 0, stream>>>(zbuf, cbbuf, cnorm, partials);
  k_reduce<<<128, 128, 0, stream>>>(partials, z, cb, o_codes);

  // zero loss/cb/cs/ew regions (atomic accumulators; scratch now dead)
  (void)hipMemsetAsync(o_loss, 0, (size_t)(OUT_TOTAL - OFF_LOSS) * sizeof(float),
                       stream);

  k_scatter<<<N_ROWS, 256, 0, stream>>>(z, cb, o_codes, o_zq, o_loss, o_cs, o_ew);
  k_ema_cs<<<KCODES / 256, 256, 0, stream>>>(ema_cs, o_cs);
  k_ema_w <<<KCODES * DIM / 256, 256, 0, stream>>>(ema_w, o_cs, o_ew, o_cb);
}

// Round 4
// 432.631 us; speedup vs baseline: 3.5052x; 1.5608x over previous
//
#include <hip/hip_runtime.h>
#include <hip/hip_bf16.h>
#include <math.h>

#define N_ROWS 16384      // 8 * 2048
#define DIM    256
#define KCODES 8192

// Output layout (float offsets), reference return order
#define OFF_ZQ    0
#define OFF_CODES 4194304
#define OFF_LOSS  4210688
#define OFF_CB    4210689
#define OFF_CS    6307841
#define OFF_EW    6316033
#define OUT_TOTAL 8413185

typedef __attribute__((ext_vector_type(8))) short bf16x8;
typedef __attribute__((ext_vector_type(4))) float f32x4;

__device__ __forceinline__ void gll16(const void* g, void* l) {
  __builtin_amdgcn_global_load_lds(
      (const __attribute__((address_space(1))) unsigned int*)g,
      (__attribute__((address_space(3))) unsigned int*)l, 16, 0, 0);
}

__device__ __forceinline__ unsigned short f2bf(float x) {
  __hip_bfloat16 h = __float2bfloat16(x);
  return *reinterpret_cast<unsigned short*>(&h);
}

// merge ordered pair (c1,i1,c2,i2) into (b1,j1,b2,j2), ties -> lower index
#define MERGE2(c1, i1, c2, i2)                                            \
  if ((c1) < b1 || ((c1) == b1 && (i1) < j1)) {                           \
    float nb2; int nj2;                                                   \
    if (b1 < (c2) || (b1 == (c2) && j1 < (i2))) { nb2 = b1; nj2 = j1; }   \
    else { nb2 = (c2); nj2 = (i2); }                                      \
    b1 = (c1); j1 = (i1); b2 = nb2; j2 = nj2;                             \
  } else if ((c1) < b2 || ((c1) == b2 && (i1) < j2)) {                    \
    b2 = (c1); j2 = (i1);                                                 \
  }

// ---------------- fp32 -> bf16 convert (8 elems/thread), scaled ----------
__global__ __launch_bounds__(256) void k_cvt(const float* __restrict__ src,
                                             unsigned short* __restrict__ dst,
                                             int n8, float scale) {
  int i = blockIdx.x * 256 + threadIdx.x;
  if (i >= n8) return;
  const float4 a = ((const float4*)src)[i * 2];
  const float4 b = ((const float4*)src)[i * 2 + 1];
  union { unsigned short u[8]; uint4 v; } o;
  o.u[0] = f2bf(scale * a.x); o.u[1] = f2bf(scale * a.y);
  o.u[2] = f2bf(scale * a.z); o.u[3] = f2bf(scale * a.w);
  o.u[4] = f2bf(scale * b.x); o.u[5] = f2bf(scale * b.y);
  o.u[6] = f2bf(scale * b.z); o.u[7] = f2bf(scale * b.w);
  ((uint4*)dst)[i] = o.v;
}

// ---------------- codebook row norms (exact fp32) ------------------------
__global__ __launch_bounds__(64) void k_cnorm(const float* __restrict__ cb,
                                              float* __restrict__ cnorm) {
  const int j = blockIdx.x;
  const int t = threadIdx.x;
  const float4 v = *(const float4*)(cb + ((size_t)j << 8) + (t << 2));
  float s = v.x * v.x + v.y * v.y + v.z * v.z + v.w * v.w;
#pragma unroll
  for (int off = 32; off >= 1; off >>= 1) s += __shfl_down(s, off);
  if (t == 0) cnorm[j] = s;
}

// ---------------- MFMA distance + per-tile top-2 (swapped operands) ------
// A = codebook (M=codes), B = z (N=rows): C[code][row]. Each lane holds 16
// codes of ONE row per nj -> in-lane top-2, then 2-step butterfly (xor 16,32).
// Accumulator seeded with ||c||^2; cbb pre-scaled by -2, so acc ends as
// b = ||c||^2 - 2 z.c directly.
__global__ __launch_bounds__(256) void k_argmin_mfma(
    const unsigned short* __restrict__ zb,   // [16384][256] bf16
    const unsigned short* __restrict__ cbb,  // [8192][256]  bf16 of (-2*c)
    const float* __restrict__ cnorm,         // [8192] fp32
    f32x4* __restrict__ partials) {          // [64][16384] {b1,j1,b2,j2}
  __shared__ __align__(16) unsigned char lds[32768];  // 2 x (8KB z + 8KB cb)

  const int tid = threadIdx.x;
  const int lane = tid & 63;
  const int w = tid >> 6;
  const int wc = w & 1;        // code half (64 codes)
  const int wr = w >> 1;       // row half  (64 rows)
  const int ct = blockIdx.x;
  const int r0 = blockIdx.y << 7;
  const int c0 = ct << 7;

  // staging: slot s = issue*256+tid -> kq=s>>7, row=s&127; LDS=[kq][row][16B]
  const int srow = tid & 127;
  const int skq = tid >> 7;
  const char* zg = (const char*)zb + (size_t)(r0 + srow) * 512 + skq * 16;
  const char* cg = (const char*)cbb + (size_t)(c0 + srow) * 512 + skq * 16;

  const int l4 = lane >> 4;    // k-quad / code sub-offset
  const int lr = lane & 15;
  int aoff[4], boff[4];
#pragma unroll
  for (int i = 0; i < 4; ++i) {
    aoff[i] = l4 * 2048 + (wc * 64 + i * 16 + lr) * 16;  // codebook rows
    boff[i] = l4 * 2048 + (wr * 64 + i * 16 + lr) * 16;  // z rows
  }

  // seed acc with cnorm (code = c0 + wc*64 + mi*16 + l4*4 + reg)
  f32x4 acc[4][4];
  {
    const f32x4* cnv = (const f32x4*)(cnorm + c0 + wc * 64 + (l4 << 2));
#pragma unroll
    for (int mi = 0; mi < 4; ++mi) {
      f32x4 cn = cnv[mi * 4];
#pragma unroll
      for (int nj = 0; nj < 4; ++nj) acc[mi][nj] = cn;
    }
  }

  // prologue stage ks=0 into buf0
  {
    unsigned char* lz = lds + tid * 16;
    unsigned char* lc = lds + 8192 + tid * 16;
    gll16(zg, lz);       gll16(zg + 32, lz + 4096);
    gll16(cg, lc);       gll16(cg + 32, lc + 4096);
  }

  int cur = 0;
  for (int ks = 0; ks < 8; ++ks) {
    __syncthreads();
    if (ks < 7) {
      const char* z1 = zg + (ks + 1) * 64;
      const char* c1 = cg + (ks + 1) * 64;
      unsigned char* lz = lds + (cur ^ 1) * 16384 + tid * 16;
      unsigned char* lc = lds + (cur ^ 1) * 16384 + 8192 + tid * 16;
      gll16(z1, lz);     gll16(z1 + 32, lz + 4096);
      gll16(c1, lc);     gll16(c1 + 32, lc + 4096);
    }
    const unsigned char* bz = lds + cur * 16384;
    const unsigned char* bc = bz + 8192;
    bf16x8 af[4], bfv[4];
#pragma unroll
    for (int i = 0; i < 4; ++i) af[i] = *(const bf16x8*)(bc + aoff[i]);
#pragma unroll
    for (int j = 0; j < 4; ++j) bfv[j] = *(const bf16x8*)(bz + boff[j]);
#pragma unroll
    for (int mi = 0; mi < 4; ++mi)
#pragma unroll
      for (int nj = 0; nj < 4; ++nj)
        acc[mi][nj] = __builtin_amdgcn_mfma_f32_16x16x32_bf16(af[mi], bfv[nj],
                                                              acc[mi][nj], 0, 0, 0);
    cur ^= 1;
  }

  // epilogue: in-lane top-2 over 16 codes per (row, nj), 2-step butterfly
  __syncthreads();                  // LDS dead; reuse as scratch
  f32x4* scr = (f32x4*)lds;         // [2 code-halves][128 rows]
  const int base_code = c0 + wc * 64 + (l4 << 2);

#pragma unroll
  for (int nj = 0; nj < 4; ++nj) {
    float b1 = 3.4e38f, b2 = 3.4e38f;
    int q1 = 0, q2 = 0;
    // ascending code order (mi*16+reg monotone) -> strict '<' = tie->lowest
#pragma unroll
    for (int mi = 0; mi < 4; ++mi)
#pragma unroll
      for (int rg = 0; rg < 4; ++rg) {
        float d = acc[mi][nj][rg];
        int q = mi * 4 + rg;
        bool u1 = d < b1;
        bool u2 = d < b2;
        float nb2 = u1 ? b1 : (u2 ? d : b2);
        int nq2 = u1 ? q1 : (u2 ? q : q2);
        b1 = u1 ? d : b1;
        q1 = u1 ? q : q1;
        b2 = nb2; q2 = nq2;
      }
    int j1 = base_code + ((q1 >> 2) << 4) + (q1 & 3);
    int j2 = base_code + ((q2 >> 2) << 4) + (q2 & 3);
#pragma unroll
    for (int m = 16; m <= 32; m <<= 1) {
      float e1 = __shfl_xor(b1, m); int i1 = __shfl_xor(j1, m);
      float e2 = __shfl_xor(b2, m); int i2 = __shfl_xor(j2, m);
      MERGE2(e1, i1, e2, i2);
    }
    if (l4 == 0) {
      f32x4 e;
      e[0] = b1; e[1] = __int_as_float(j1);
      e[2] = b2; e[3] = __int_as_float(j2);
      scr[wc * 128 + wr * 64 + nj * 16 + lr] = e;
    }
  }
  __syncthreads();
  if (tid < 128) {
    f32x4 e0 = scr[tid], e1v = scr[128 + tid];
    float b1 = e0[0], b2 = e0[2];
    int j1 = __float_as_int(e0[1]), j2 = __float_as_int(e0[3]);
    float e1 = e1v[0], e2 = e1v[2];
    int i1 = __float_as_int(e1v[1]), i2 = __float_as_int(e1v[3]);
    MERGE2(e1, i1, e2, i2);
    f32x4 e;
    e[0] = b1; e[1] = __int_as_float(j1);
    e[2] = b2; e[3] = __int_as_float(j2);
    partials[(size_t)ct * 16384 + r0 + tid] = e;
  }
}

// ---------------- merge partials + exact refine ---------------------------
__global__ __launch_bounds__(128) void k_reduce(
    const f32x4* __restrict__ partials, const float* __restrict__ z,
    const float* __restrict__ cb, float* __restrict__ out_codes) {
  const int row = blockIdx.x * 128 + threadIdx.x;
  float b1 = 3.4e38f, b2 = 3.4e38f;
  int j1 = 0x7fffffff, j2 = 0x7fffffff;
  for (int ct = 0; ct < 64; ++ct) {
    f32x4 e = partials[(size_t)ct * 16384 + row];
    float c1 = e[0], c2 = e[2];
    int i1 = __float_as_int(e[1]), i2 = __float_as_int(e[3]);
    MERGE2(c1, i1, c2, i2);
  }
  int chosen = j1;
  if (b2 - b1 < 0.5f) {
    const float* zr = z + ((size_t)row << 8);
    const float win = b1 + 0.5f;
    double bestd = 1e300; int bestj = 0x7fffffff;
    for (int ct = 0; ct < 64; ++ct) {
      f32x4 e = partials[(size_t)ct * 16384 + row];
#pragma unroll
      for (int h = 0; h < 2; ++h) {
        float bv = h ? e[2] : e[0];
        int jv = __float_as_int(h ? e[3] : e[1]);
        if (bv <= win && jv != 0x7fffffff) {
          const float* c = cb + ((size_t)jv << 8);
          double d = 0.0;
          for (int k = 0; k < DIM; ++k) {
            double df = (double)zr[k] - (double)c[k];
            d += df * df;
          }
          if (d < bestd || (d == bestd && jv < bestj)) { bestd = d; bestj = jv; }
        }
      }
    }
    chosen = bestj;
  }
  out_codes[row] = (float)chosen;
}

// ---------------- sorted EMA path (no bulk atomics) -----------------------
__global__ __launch_bounds__(256) void k_hist(const float* __restrict__ codesf,
                                              int* __restrict__ cnt) {
  int i = blockIdx.x * 256 + threadIdx.x;
  atomicAdd(&cnt[(int)codesf[i]], 1);
}

__global__ __launch_bounds__(1024) void k_scan(
    const int* __restrict__ cnt, int* __restrict__ start,
    int* __restrict__ cursor, const float* __restrict__ ema_cs,
    float* __restrict__ cs_out) {
  __shared__ int ssum[1024];
  const int t = threadIdx.x;
  const int base = t * 8;
  int c[8], s = 0;
#pragma unroll
  for (int i = 0; i < 8; ++i) { c[i] = cnt[base + i]; s += c[i]; }
  ssum[t] = s;
  __syncthreads();
  for (int off = 1; off < 1024; off <<= 1) {
    int v = 0;
    if (t >= off) v = ssum[t - off];
    __syncthreads();
    ssum[t] += v;
    __syncthreads();
  }
  int ex = ssum[t] - s;  // exclusive base
#pragma unroll
  for (int i = 0; i < 8; ++i) {
    start[base + i] = ex;
    cursor[base + i] = ex;
    cs_out[base + i] = 0.99f * ema_cs[base + i] + 0.01f * (float)c[i];
    ex += c[i];
  }
}

__global__ __launch_bounds__(256) void k_place(const float* __restrict__ codesf,
                                               int* __restrict__ cursor,
                                               int* __restrict__ rowlist) {
  int i = blockIdx.x * 256 + threadIdx.x;
  int c = (int)codesf[i];
  int p = atomicAdd(&cursor[c], 1);
  rowlist[p] = i;
}

// gather z_q + spread-slot loss partials (no ew/cs atomics)
__global__ __launch_bounds__(256) void k_scatter2(
    const float* __restrict__ z, const float* __restrict__ cb,
    const float* __restrict__ codesf, float* __restrict__ zq,
    float* __restrict__ loss_part) {
  const int row = blockIdx.x;
  const int d = threadIdx.x;
  const int c = (int)codesf[row];
  const float zv = z[((size_t)row << 8) + d];
  const float qv = cb[((size_t)c << 8) + d];
  zq[((size_t)row << 8) + d] = zv + (qv - zv);
  float diff = zv - qv;
  float sq = diff * diff;
#pragma unroll
  for (int off = 32; off >= 1; off >>= 1) sq += __shfl_down(sq, off);
  __shared__ float wpart[4];
  if ((d & 63) == 0) wpart[d >> 6] = sq;
  __syncthreads();
  if (d == 0) {
    float s = (wpart[0] + wpart[1]) + (wpart[2] + wpart[3]);
    atomicAdd(loss_part + (row & 255), s * (float)(0.1 / 4194304.0));
  }
}

__global__ __launch_bounds__(256) void k_loss_final(
    const float* __restrict__ part, float* __restrict__ loss) {
  float s = part[threadIdx.x];
#pragma unroll
  for (int off = 32; off >= 1; off >>= 1) s += __shfl_down(s, off);
  __shared__ float w[4];
  if ((threadIdx.x & 63) == 0) w[threadIdx.x >> 6] = s;
  __syncthreads();
  if (threadIdx.x == 0) loss[0] = (w[0] + w[1]) + (w[2] + w[3]);
}

// per-code dw gather + EMA + codebook divide (block = one code)
__global__ __launch_bounds__(256) void k_dw(
    const float* __restrict__ z, const int* __restrict__ start,
    const int* __restrict__ cnt, const int* __restrict__ rowlist,
    const float* __restrict__ ema_w, const float* __restrict__ cs_new,
    float* __restrict__ ew, float* __restrict__ cb_out) {
  const int k = blockIdx.x;
  const int d = threadIdx.x;
  const int s = start[k], n = cnt[k];
  float a = 0.0f;
  for (int t = 0; t < n; ++t)
    a += z[((size_t)rowlist[s + t] << 8) + d];
  const size_t o = ((size_t)k << 8) + d;
  const float v = 0.99f * ema_w[o] + 0.01f * a;
  ew[o] = v;
  cb_out[o] = v / (cs_new[k] + 1e-5f);
}

// ---------------- fallback atomic path (ws too small) ---------------------
__global__ __launch_bounds__(256) void k_scatter(
    const float* __restrict__ z, const float* __restrict__ cb,
    const float* __restrict__ codesf, float* __restrict__ zq,
    float* __restrict__ loss, float* __restrict__ cs_acc,
    float* __restrict__ ew_acc) {
  const int row = blockIdx.x;
  const int d = threadIdx.x;
  const int c = (int)codesf[row];
  const float zv = z[((size_t)row << 8) + d];
  const float qv = cb[((size_t)c << 8) + d];
  zq[((size_t)row << 8) + d] = zv + (qv - zv);
  float diff = zv - qv;
  float sq = diff * diff;
#pragma unroll
  for (int off = 32; off >= 1; off >>= 1) sq += __shfl_down(sq, off);
  __shared__ float wpart[4];
  if ((d & 63) == 0) wpart[d >> 6] = sq;
  __syncthreads();
  if (d == 0) {
    float s = (wpart[0] + wpart[1]) + (wpart[2] + wpart[3]);
    atomicAdd(loss, s * (float)(0.1 / 4194304.0));
    atomicAdd(cs_acc + c, 1.0f);
  }
  atomicAdd(ew_acc + ((size_t)c << 8) + d, zv);
}

__global__ __launch_bounds__(256) void k_ema_cs(const float* __restrict__ ema_cs,
                                                float* __restrict__ cs_io) {
  const int k = blockIdx.x * 256 + threadIdx.x;
  const float cnt = cs_io[k];
  cs_io[k] = 0.99f * ema_cs[k] + 0.01f * cnt;
}

__global__ __launch_bounds__(256) void k_ema_w(const float* __restrict__ ema_w,
                                               const float* __restrict__ cs_new,
                                               float* __restrict__ ew_io,
                                               float* __restrict__ cb_out) {
  const int i = blockIdx.x * 256 + threadIdx.x;
  const float dw = ew_io[i];
  const float v = 0.99f * ema_w[i] + 0.01f * dw;
  ew_io[i] = v;
  cb_out[i] = v / (cs_new[i >> 8] + 1e-5f);
}

// ---------------- launch --------------------------------------------------
extern "C" void kernel_launch(void* const* d_in, const int* in_sizes, int n_in,
                              void* d_out, int out_size, void* d_ws, size_t ws_size,
                              hipStream_t stream) {
  const float* z      = (const float*)d_in[0];
  const float* cb     = (const float*)d_in[1];
  const float* ema_cs = (const float*)d_in[2];
  const float* ema_w  = (const float*)d_in[3];
  float* out = (float*)d_out;

  float* o_zq    = out + OFF_ZQ;
  float* o_codes = out + OFF_CODES;
  float* o_loss  = out + OFF_LOSS;
  float* o_cb    = out + OFF_CB;
  float* o_cs    = out + OFF_CS;
  float* o_ew    = out + OFF_EW;

  // scratch aliases inside output regions (each overwritten later in order):
  //   z_bf16 (8.39MB)                 -> o_cb region
  //   cb_bf16 (4.19MB) + cnorm (32KB) -> o_ew region
  //   partials (16.78MB exact)        -> o_zq region
  uintptr_t zb_a  = ((uintptr_t)o_cb + 15) & ~(uintptr_t)15;
  uintptr_t cbb_a = ((uintptr_t)o_ew + 15) & ~(uintptr_t)15;
  unsigned short* zbuf  = (unsigned short*)zb_a;
  unsigned short* cbbuf = (unsigned short*)cbb_a;
  float* cnorm = (float*)(cbb_a + 4194304);
  f32x4* partials = (f32x4*)o_zq;

  k_cvt<<<2048, 256, 0, stream>>>(z, zbuf, 524288, 1.0f);
  k_cvt<<<1024, 256, 0, stream>>>(cb, cbbuf, 262144, -2.0f);  // -2c, exact
  k_cnorm<<<KCODES, 64, 0, stream>>>(cb, cnorm);

  dim3 g(64, 128);
  k_argmin_mfma<<<g, 256, 0, stream>>>(zbuf, cbbuf, cnorm, partials);
  k_reduce<<<128, 128, 0, stream>>>(partials, z, cb, o_codes);

  const size_t ws_need = 4 * (8192 * 3 + 16384 + 256);  // 164864 B
  if (ws_size >= ws_need) {
    int* cnt      = (int*)d_ws;
    int* start    = cnt + 8192;
    int* cursor   = start + 8192;
    int* rowlist  = cursor + 8192;
    float* loss_part = (float*)(rowlist + 16384);
    (void)hipMemsetAsync(d_ws, 0, ws_need, stream);
    k_hist <<<64, 256, 0, stream>>>(o_codes, cnt);
    k_scan <<<1, 1024, 0, stream>>>(cnt, start, cursor, ema_cs, o_cs);
    k_place<<<64, 256, 0, stream>>>(o_codes, cursor, rowlist);
    k_scatter2<<<N_ROWS, 256, 0, stream>>>(z, cb, o_codes, o_zq, loss_part);
    k_loss_final<<<1, 256, 0, stream>>>(loss_part, o_loss);
    k_dw<<<KCODES, 256, 0, stream>>>(z, start, cnt, rowlist, ema_w, o_cs,
                                     o_ew, o_cb);
  } else {
    (void)hipMemsetAsync(o_loss, 0,
                         (size_t)(OUT_TOTAL - OFF_LOSS) * sizeof(float), stream);
    k_scatter<<<N_ROWS, 256, 0, stream>>>(z, cb, o_codes, o_zq, o_loss, o_cs,
                                          o_ew);
    k_ema_cs<<<KCODES / 256, 256, 0, stream>>>(ema_cs, o_cs);
    k_ema_w <<<KCODES * DIM / 256, 256, 0, stream>>>(ema_w, o_cs, o_ew, o_cb);
  }
}

// Round 5
// 302.809 us; speedup vs baseline: 5.0079x; 1.4287x over previous
//
#include <hip/hip_runtime.h>
#include <hip/hip_bf16.h>
#include <math.h>

#define N_ROWS 16384      // 8 * 2048
#define DIM    256
#define KCODES 8192

// Output layout (float offsets), reference return order
#define OFF_ZQ    0
#define OFF_CODES 4194304
#define OFF_LOSS  4210688
#define OFF_CB    4210689
#define OFF_CS    6307841
#define OFF_EW    6316033
#define OUT_TOTAL 8413185

typedef __attribute__((ext_vector_type(8))) short bf16x8;
typedef __attribute__((ext_vector_type(4))) float f32x4;

__device__ __forceinline__ void gll16(const void* g, void* l) {
  __builtin_amdgcn_global_load_lds(
      (const __attribute__((address_space(1))) unsigned int*)g,
      (__attribute__((address_space(3))) unsigned int*)l, 16, 0, 0);
}

__device__ __forceinline__ unsigned short f2bf(float x) {
  __hip_bfloat16 h = __float2bfloat16(x);
  return *reinterpret_cast<unsigned short*>(&h);
}

// merge ordered pair (c1,i1,c2,i2) into (b1,j1,b2,j2), ties -> lower index
#define MERGE2(c1, i1, c2, i2)                                            \
  if ((c1) < b1 || ((c1) == b1 && (i1) < j1)) {                           \
    float nb2; int nj2;                                                   \
    if (b1 < (c2) || (b1 == (c2) && j1 < (i2))) { nb2 = b1; nj2 = j1; }   \
    else { nb2 = (c2); nj2 = (i2); }                                      \
    b1 = (c1); j1 = (i1); b2 = nb2; j2 = nj2;                             \
  } else if ((c1) < b2 || ((c1) == b2 && (i1) < j2)) {                    \
    b2 = (c1); j2 = (i1);                                                 \
  }

// ---------------- fp32 -> bf16 convert (8 elems/thread), scaled ----------
__global__ __launch_bounds__(256) void k_cvt(const float* __restrict__ src,
                                             unsigned short* __restrict__ dst,
                                             int n8, float scale) {
  int i = blockIdx.x * 256 + threadIdx.x;
  if (i >= n8) return;
  const float4 a = ((const float4*)src)[i * 2];
  const float4 b = ((const float4*)src)[i * 2 + 1];
  union { unsigned short u[8]; uint4 v; } o;
  o.u[0] = f2bf(scale * a.x); o.u[1] = f2bf(scale * a.y);
  o.u[2] = f2bf(scale * a.z); o.u[3] = f2bf(scale * a.w);
  o.u[4] = f2bf(scale * b.x); o.u[5] = f2bf(scale * b.y);
  o.u[6] = f2bf(scale * b.z); o.u[7] = f2bf(scale * b.w);
  ((uint4*)dst)[i] = o.v;
}

// ---------------- codebook row norms (exact fp32) ------------------------
__global__ __launch_bounds__(64) void k_cnorm(const float* __restrict__ cb,
                                              float* __restrict__ cnorm) {
  const int j = blockIdx.x;
  const int t = threadIdx.x;
  const float4 v = *(const float4*)(cb + ((size_t)j << 8) + (t << 2));
  float s = v.x * v.x + v.y * v.y + v.z * v.z + v.w * v.w;
#pragma unroll
  for (int off = 32; off >= 1; off >>= 1) s += __shfl_down(s, off);
  if (t == 0) cnorm[j] = s;
}

// ---------------- MFMA distance + per-tile top-2 (swapped operands) ------
// A = codebook (M=codes), B = z (N=rows): C[code][row]. Each lane holds 16
// codes of ONE row per nj -> in-lane top-2, then 2-step butterfly (xor 16,32).
// Accumulator seeded with ||c||^2; cbb pre-scaled by -2, so acc ends as
// b = ||c||^2 - 2 z.c directly. Partials written TRANSPOSED: [row][64 ct].
__global__ __launch_bounds__(256) void k_argmin_mfma(
    const unsigned short* __restrict__ zb,   // [16384][256] bf16
    const unsigned short* __restrict__ cbb,  // [8192][256]  bf16 of (-2*c)
    const float* __restrict__ cnorm,         // [8192] fp32
    f32x4* __restrict__ partials) {          // [16384][64] {b1,j1,b2,j2}
  __shared__ __align__(16) unsigned char lds[32768];  // 2 x (8KB z + 8KB cb)

  const int tid = threadIdx.x;
  const int lane = tid & 63;
  const int w = tid >> 6;
  const int wc = w & 1;        // code half (64 codes)
  const int wr = w >> 1;       // row half  (64 rows)
  const int ct = blockIdx.x;
  const int r0 = blockIdx.y << 7;
  const int c0 = ct << 7;

  // staging: slot s = issue*256+tid -> kq=s>>7, row=s&127; LDS=[kq][row][16B]
  const int srow = tid & 127;
  const int skq = tid >> 7;
  const char* zg = (const char*)zb + (size_t)(r0 + srow) * 512 + skq * 16;
  const char* cg = (const char*)cbb + (size_t)(c0 + srow) * 512 + skq * 16;

  const int l4 = lane >> 4;    // k-quad / code sub-offset
  const int lr = lane & 15;
  int aoff[4], boff[4];
#pragma unroll
  for (int i = 0; i < 4; ++i) {
    aoff[i] = l4 * 2048 + (wc * 64 + i * 16 + lr) * 16;  // codebook rows
    boff[i] = l4 * 2048 + (wr * 64 + i * 16 + lr) * 16;  // z rows
  }

  // seed acc with cnorm (code = c0 + wc*64 + mi*16 + l4*4 + reg)
  f32x4 acc[4][4];
  {
    const f32x4* cnv = (const f32x4*)(cnorm + c0 + wc * 64 + (l4 << 2));
#pragma unroll
    for (int mi = 0; mi < 4; ++mi) {
      f32x4 cn = cnv[mi * 4];
#pragma unroll
      for (int nj = 0; nj < 4; ++nj) acc[mi][nj] = cn;
    }
  }

  // prologue stage ks=0 into buf0
  {
    unsigned char* lz = lds + tid * 16;
    unsigned char* lc = lds + 8192 + tid * 16;
    gll16(zg, lz);       gll16(zg + 32, lz + 4096);
    gll16(cg, lc);       gll16(cg + 32, lc + 4096);
  }

  int cur = 0;
  for (int ks = 0; ks < 8; ++ks) {
    __syncthreads();
    if (ks < 7) {
      const char* z1 = zg + (ks + 1) * 64;
      const char* c1 = cg + (ks + 1) * 64;
      unsigned char* lz = lds + (cur ^ 1) * 16384 + tid * 16;
      unsigned char* lc = lds + (cur ^ 1) * 16384 + 8192 + tid * 16;
      gll16(z1, lz);     gll16(z1 + 32, lz + 4096);
      gll16(c1, lc);     gll16(c1 + 32, lc + 4096);
    }
    const unsigned char* bz = lds + cur * 16384;
    const unsigned char* bc = bz + 8192;
    bf16x8 af[4], bfv[4];
#pragma unroll
    for (int i = 0; i < 4; ++i) af[i] = *(const bf16x8*)(bc + aoff[i]);
#pragma unroll
    for (int j = 0; j < 4; ++j) bfv[j] = *(const bf16x8*)(bz + boff[j]);
#pragma unroll
    for (int mi = 0; mi < 4; ++mi)
#pragma unroll
      for (int nj = 0; nj < 4; ++nj)
        acc[mi][nj] = __builtin_amdgcn_mfma_f32_16x16x32_bf16(af[mi], bfv[nj],
                                                              acc[mi][nj], 0, 0, 0);
    cur ^= 1;
  }

  // epilogue: in-lane top-2 over 16 codes per (row, nj), 2-step butterfly
  __syncthreads();                  // LDS dead; reuse as scratch
  f32x4* scr = (f32x4*)lds;         // [2 code-halves][128 rows]
  const int base_code = c0 + wc * 64 + (l4 << 2);

#pragma unroll
  for (int nj = 0; nj < 4; ++nj) {
    float b1 = 3.4e38f, b2 = 3.4e38f;
    int q1 = 0, q2 = 0;
    // ascending code order (mi*16+reg monotone) -> strict '<' = tie->lowest
#pragma unroll
    for (int mi = 0; mi < 4; ++mi)
#pragma unroll
      for (int rg = 0; rg < 4; ++rg) {
        float d = acc[mi][nj][rg];
        int q = mi * 4 + rg;
        bool u1 = d < b1;
        bool u2 = d < b2;
        float nb2 = u1 ? b1 : (u2 ? d : b2);
        int nq2 = u1 ? q1 : (u2 ? q : q2);
        b1 = u1 ? d : b1;
        q1 = u1 ? q : q1;
        b2 = nb2; q2 = nq2;
      }
    int j1 = base_code + ((q1 >> 2) << 4) + (q1 & 3);
    int j2 = base_code + ((q2 >> 2) << 4) + (q2 & 3);
#pragma unroll
    for (int m = 16; m <= 32; m <<= 1) {
      float e1 = __shfl_xor(b1, m); int i1 = __shfl_xor(j1, m);
      float e2 = __shfl_xor(b2, m); int i2 = __shfl_xor(j2, m);
      MERGE2(e1, i1, e2, i2);
    }
    if (l4 == 0) {
      f32x4 e;
      e[0] = b1; e[1] = __int_as_float(j1);
      e[2] = b2; e[3] = __int_as_float(j2);
      scr[wc * 128 + wr * 64 + nj * 16 + lr] = e;
    }
  }
  __syncthreads();
  if (tid < 128) {
    f32x4 e0 = scr[tid], e1v = scr[128 + tid];
    float b1 = e0[0], b2 = e0[2];
    int j1 = __float_as_int(e0[1]), j2 = __float_as_int(e0[3]);
    float e1 = e1v[0], e2 = e1v[2];
    int i1 = __float_as_int(e1v[1]), i2 = __float_as_int(e1v[3]);
    MERGE2(e1, i1, e2, i2);
    f32x4 e;
    e[0] = b1; e[1] = __int_as_float(j1);
    e[2] = b2; e[3] = __int_as_float(j2);
    partials[(size_t)(r0 + tid) * 64 + ct] = e;  // transposed: [row][ct]
  }
}

// ---------------- merge partials + exact refine (wave per row) ------------
__global__ __launch_bounds__(256) void k_reduce(
    const f32x4* __restrict__ partials, const float* __restrict__ z,
    const float* __restrict__ cb, float* __restrict__ out_codes) {
  const int row = blockIdx.x * 4 + (threadIdx.x >> 6);
  const int lane = threadIdx.x & 63;

  // lane l owns code-tile l's top-2
  f32x4 e = partials[(size_t)row * 64 + lane];
  const float ob1 = e[0], ob2 = e[2];
  const int oj1 = __float_as_int(e[1]), oj2 = __float_as_int(e[3]);

  float b1 = ob1, b2 = ob2;
  int j1 = oj1, j2 = oj2;
#pragma unroll
  for (int m = 1; m <= 32; m <<= 1) {
    float c1 = __shfl_xor(b1, m); int i1 = __shfl_xor(j1, m);
    float c2 = __shfl_xor(b2, m); int i2 = __shfl_xor(j2, m);
    MERGE2(c1, i1, c2, i2);
  }
  int chosen = j1;   // all lanes agree after butterfly

  if (b2 - b1 < 0.5f) {   // wave-uniform branch
    // exact fp64 re-eval of every candidate within the noise window;
    // each lane handles its own tile's two candidates (same set as before)
    const float win = b1 + 0.5f;
    const float* zr = z + ((size_t)row << 8);
    double bestd = 1e300; int bestj = 0x7fffffff;
#pragma unroll
    for (int h = 0; h < 2; ++h) {
      float bv = h ? ob2 : ob1;
      int jv = h ? oj2 : oj1;
      if (bv <= win && jv != 0x7fffffff) {
        const float* c = cb + ((size_t)jv << 8);
        double d = 0.0;
        for (int k = 0; k < DIM; ++k) {
          double df = (double)zr[k] - (double)c[k];
          d += df * df;
        }
        if (d < bestd || (d == bestd && jv < bestj)) { bestd = d; bestj = jv; }
      }
    }
#pragma unroll
    for (int m = 1; m <= 32; m <<= 1) {
      double od = __shfl_xor(bestd, m);
      int oj = __shfl_xor(bestj, m);
      if (od < bestd || (od == bestd && oj < bestj)) { bestd = od; bestj = oj; }
    }
    chosen = bestj;
  }
  if (lane == 0) out_codes[row] = (float)chosen;
}

// ---------------- sorted EMA path (no bulk atomics) -----------------------
__global__ __launch_bounds__(256) void k_hist(const float* __restrict__ codesf,
                                              int* __restrict__ cnt) {
  int i = blockIdx.x * 256 + threadIdx.x;
  atomicAdd(&cnt[(int)codesf[i]], 1);
}

__global__ __launch_bounds__(1024) void k_scan(
    const int* __restrict__ cnt, int* __restrict__ start,
    int* __restrict__ cursor, const float* __restrict__ ema_cs,
    float* __restrict__ cs_out) {
  __shared__ int ssum[1024];
  const int t = threadIdx.x;
  const int base = t * 8;
  int c[8], s = 0;
#pragma unroll
  for (int i = 0; i < 8; ++i) { c[i] = cnt[base + i]; s += c[i]; }
  ssum[t] = s;
  __syncthreads();
  for (int off = 1; off < 1024; off <<= 1) {
    int v = 0;
    if (t >= off) v = ssum[t - off];
    __syncthreads();
    ssum[t] += v;
    __syncthreads();
  }
  int ex = ssum[t] - s;  // exclusive base
#pragma unroll
  for (int i = 0; i < 8; ++i) {
    start[base + i] = ex;
    cursor[base + i] = ex;
    cs_out[base + i] = 0.99f * ema_cs[base + i] + 0.01f * (float)c[i];
    ex += c[i];
  }
}

__global__ __launch_bounds__(256) void k_place(const float* __restrict__ codesf,
                                               int* __restrict__ cursor,
                                               int* __restrict__ rowlist) {
  int i = blockIdx.x * 256 + threadIdx.x;
  int c = (int)codesf[i];
  int p = atomicAdd(&cursor[c], 1);
  rowlist[p] = i;
}

// gather z_q + spread-slot loss partials (no ew/cs atomics)
__global__ __launch_bounds__(256) void k_scatter2(
    const float* __restrict__ z, const float* __restrict__ cb,
    const float* __restrict__ codesf, float* __restrict__ zq,
    float* __restrict__ loss_part) {
  const int row = blockIdx.x;
  const int d = threadIdx.x;
  const int c = (int)codesf[row];
  const float zv = z[((size_t)row << 8) + d];
  const float qv = cb[((size_t)c << 8) + d];
  zq[((size_t)row << 8) + d] = zv + (qv - zv);
  float diff = zv - qv;
  float sq = diff * diff;
#pragma unroll
  for (int off = 32; off >= 1; off >>= 1) sq += __shfl_down(sq, off);
  __shared__ float wpart[4];
  if ((d & 63) == 0) wpart[d >> 6] = sq;
  __syncthreads();
  if (d == 0) {
    float s = (wpart[0] + wpart[1]) + (wpart[2] + wpart[3]);
    atomicAdd(loss_part + (row & 255), s * (float)(0.1 / 4194304.0));
  }
}

__global__ __launch_bounds__(256) void k_loss_final(
    const float* __restrict__ part, float* __restrict__ loss) {
  float s = part[threadIdx.x];
#pragma unroll
  for (int off = 32; off >= 1; off >>= 1) s += __shfl_down(s, off);
  __shared__ float w[4];
  if ((threadIdx.x & 63) == 0) w[threadIdx.x >> 6] = s;
  __syncthreads();
  if (threadIdx.x == 0) loss[0] = (w[0] + w[1]) + (w[2] + w[3]);
}

// per-code dw gather + EMA + codebook divide (block = one code)
__global__ __launch_bounds__(256) void k_dw(
    const float* __restrict__ z, const int* __restrict__ start,
    const int* __restrict__ cnt, const int* __restrict__ rowlist,
    const float* __restrict__ ema_w, const float* __restrict__ cs_new,
    float* __restrict__ ew, float* __restrict__ cb_out) {
  const int k = blockIdx.x;
  const int d = threadIdx.x;
  const int s = start[k], n = cnt[k];
  float a = 0.0f;
  for (int t = 0; t < n; ++t)
    a += z[((size_t)rowlist[s + t] << 8) + d];
  const size_t o = ((size_t)k << 8) + d;
  const float v = 0.99f * ema_w[o] + 0.01f * a;
  ew[o] = v;
  cb_out[o] = v / (cs_new[k] + 1e-5f);
}

// ---------------- fallback atomic path (ws too small) ---------------------
__global__ __launch_bounds__(256) void k_scatter(
    const float* __restrict__ z, const float* __restrict__ cb,
    const float* __restrict__ codesf, float* __restrict__ zq,
    float* __restrict__ loss, float* __restrict__ cs_acc,
    float* __restrict__ ew_acc) {
  const int row = blockIdx.x;
  const int d = threadIdx.x;
  const int c = (int)codesf[row];
  const float zv = z[((size_t)row << 8) + d];
  const float qv = cb[((size_t)c << 8) + d];
  zq[((size_t)row << 8) + d] = zv + (qv - zv);
  float diff = zv - qv;
  float sq = diff * diff;
#pragma unroll
  for (int off = 32; off >= 1; off >>= 1) sq += __shfl_down(sq, off);
  __shared__ float wpart[4];
  if ((d & 63) == 0) wpart[d >> 6] = sq;
  __syncthreads();
  if (d == 0) {
    float s = (wpart[0] + wpart[1]) + (wpart[2] + wpart[3]);
    atomicAdd(loss, s * (float)(0.1 / 4194304.0));
    atomicAdd(cs_acc + c, 1.0f);
  }
  atomicAdd(ew_acc + ((size_t)c << 8) + d, zv);
}

__global__ __launch_bounds__(256) void k_ema_cs(const float* __restrict__ ema_cs,
                                                float* __restrict__ cs_io) {
  const int k = blockIdx.x * 256 + threadIdx.x;
  const float cnt = cs_io[k];
  cs_io[k] = 0.99f * ema_cs[k] + 0.01f * cnt;
}

__global__ __launch_bounds__(256) void k_ema_w(const float* __restrict__ ema_w,
                                               const float* __restrict__ cs_new,
                                               float* __restrict__ ew_io,
                                               float* __restrict__ cb_out) {
  const int i = blockIdx.x * 256 + threadIdx.x;
  const float dw = ew_io[i];
  const float v = 0.99f * ema_w[i] + 0.01f * dw;
  ew_io[i] = v;
  cb_out[i] = v / (cs_new[i >> 8] + 1e-5f);
}

// ---------------- launch --------------------------------------------------
extern "C" void kernel_launch(void* const* d_in, const int* in_sizes, int n_in,
                              void* d_out, int out_size, void* d_ws, size_t ws_size,
                              hipStream_t stream) {
  const float* z      = (const float*)d_in[0];
  const float* cb     = (const float*)d_in[1];
  const float* ema_cs = (const float*)d_in[2];
  const float* ema_w  = (const float*)d_in[3];
  float* out = (float*)d_out;

  float* o_zq    = out + OFF_ZQ;
  float* o_codes = out + OFF_CODES;
  float* o_loss  = out + OFF_LOSS;
  float* o_cb    = out + OFF_CB;
  float* o_cs    = out + OFF_CS;
  float* o_ew    = out + OFF_EW;

  // scratch aliases inside output regions (each overwritten later in order):
  //   z_bf16 (8.39MB)                 -> o_cb region
  //   cb_bf16 (4.19MB) + cnorm (32KB) -> o_ew region
  //   partials (16.78MB exact)        -> o_zq region
  uintptr_t zb_a  = ((uintptr_t)o_cb + 15) & ~(uintptr_t)15;
  uintptr_t cbb_a = ((uintptr_t)o_ew + 15) & ~(uintptr_t)15;
  unsigned short* zbuf  = (unsigned short*)zb_a;
  unsigned short* cbbuf = (unsigned short*)cbb_a;
  float* cnorm = (float*)(cbb_a + 4194304);
  f32x4* partials = (f32x4*)o_zq;

  k_cvt<<<2048, 256, 0, stream>>>(z, zbuf, 524288, 1.0f);
  k_cvt<<<1024, 256, 0, stream>>>(cb, cbbuf, 262144, -2.0f);  // -2c, exact
  k_cnorm<<<KCODES, 64, 0, stream>>>(cb, cnorm);

  dim3 g(64, 128);
  k_argmin_mfma<<<g, 256, 0, stream>>>(zbuf, cbbuf, cnorm, partials);
  k_reduce<<<N_ROWS / 4, 256, 0, stream>>>(partials, z, cb, o_codes);

  const size_t ws_need = 4 * (8192 * 3 + 16384 + 256);  // 164864 B
  if (ws_size >= ws_need) {
    int* cnt      = (int*)d_ws;
    int* start    = cnt + 8192;
    int* cursor   = start + 8192;
    int* rowlist  = cursor + 8192;
    float* loss_part = (float*)(rowlist + 16384);
    (void)hipMemsetAsync(d_ws, 0, ws_need, stream);
    k_hist <<<64, 256, 0, stream>>>(o_codes, cnt);
    k_scan <<<1, 1024, 0, stream>>>(cnt, start, cursor, ema_cs, o_cs);
    k_place<<<64, 256, 0, stream>>>(o_codes, cursor, rowlist);
    k_scatter2<<<N_ROWS, 256, 0, stream>>>(z, cb, o_codes, o_zq, loss_part);
    k_loss_final<<<1, 256, 0, stream>>>(loss_part, o_loss);
    k_dw<<<KCODES, 256, 0, stream>>>(z, start, cnt, rowlist, ema_w, o_cs,
                                     o_ew, o_cb);
  } else {
    (void)hipMemsetAsync(o_loss, 0,
                         (size_t)(OUT_TOTAL - OFF_LOSS) * sizeof(float), stream);
    k_scatter<<<N_ROWS, 256, 0, stream>>>(z, cb, o_codes, o_zq, o_loss, o_cs,
                                          o_ew);
    k_ema_cs<<<KCODES / 256, 256, 0, stream>>>(ema_cs, o_cs);
    k_ema_w <<<KCODES * DIM / 256, 256, 0, stream>>>(ema_w, o_cs, o_ew, o_cb);
  }
}

// Round 6
// 282.304 us; speedup vs baseline: 5.3717x; 1.0726x over previous
//
#include <hip/hip_runtime.h>
#include <hip/hip_bf16.h>
#include <math.h>

#define N_ROWS 16384      // 8 * 2048
#define DIM    256
#define KCODES 8192

// Output layout (float offsets), reference return order
#define OFF_ZQ    0
#define OFF_CODES 4194304
#define OFF_LOSS  4210688
#define OFF_CB    4210689
#define OFF_CS    6307841
#define OFF_EW    6316033
#define OUT_TOTAL 8413185

typedef __attribute__((ext_vector_type(8))) short bf16x8;
typedef __attribute__((ext_vector_type(4))) float f32x4;

__device__ __forceinline__ void gll16(const void* g, void* l) {
  __builtin_amdgcn_global_load_lds(
      (const __attribute__((address_space(1))) unsigned int*)g,
      (__attribute__((address_space(3))) unsigned int*)l, 16, 0, 0);
}

__device__ __forceinline__ unsigned short f2bf(float x) {
  __hip_bfloat16 h = __float2bfloat16(x);
  return *reinterpret_cast<unsigned short*>(&h);
}

// merge ordered pair (c1,i1,c2,i2) into (b1,j1,b2,j2), ties -> lower index
#define MERGE2(c1, i1, c2, i2)                                            \
  if ((c1) < b1 || ((c1) == b1 && (i1) < j1)) {                           \
    float nb2; int nj2;                                                   \
    if (b1 < (c2) || (b1 == (c2) && j1 < (i2))) { nb2 = b1; nj2 = j1; }   \
    else { nb2 = (c2); nj2 = (i2); }                                      \
    b1 = (c1); j1 = (i1); b2 = nb2; j2 = nj2;                             \
  } else if ((c1) < b2 || ((c1) == b2 && (i1) < j2)) {                    \
    b2 = (c1); j2 = (i1);                                                 \
  }

// ---------------- fp32 -> bf16 convert (z, 8 elems/thread) ---------------
__global__ __launch_bounds__(256) void k_cvt(const float* __restrict__ src,
                                             unsigned short* __restrict__ dst,
                                             int n8) {
  int i = blockIdx.x * 256 + threadIdx.x;
  if (i >= n8) return;
  const float4 a = ((const float4*)src)[i * 2];
  const float4 b = ((const float4*)src)[i * 2 + 1];
  union { unsigned short u[8]; uint4 v; } o;
  o.u[0] = f2bf(a.x); o.u[1] = f2bf(a.y); o.u[2] = f2bf(a.z); o.u[3] = f2bf(a.w);
  o.u[4] = f2bf(b.x); o.u[5] = f2bf(b.y); o.u[6] = f2bf(b.z); o.u[7] = f2bf(b.w);
  ((uint4*)dst)[i] = o.v;
}

// ---------------- fused: cb -> bf16(-2c) + ||c||^2 -----------------------
__global__ __launch_bounds__(256) void k_prep(const float* __restrict__ cb,
                                              unsigned short* __restrict__ cbbuf,
                                              float* __restrict__ cnorm) {
  const int w = threadIdx.x >> 6, t = threadIdx.x & 63;
  const int j = blockIdx.x * 4 + w;
  const float4 v = *(const float4*)(cb + ((size_t)j << 8) + (t << 2));
  union { unsigned short u[4]; uint2 d2; } o;
  o.u[0] = f2bf(-2.0f * v.x); o.u[1] = f2bf(-2.0f * v.y);
  o.u[2] = f2bf(-2.0f * v.z); o.u[3] = f2bf(-2.0f * v.w);
  *(uint2*)(cbbuf + ((size_t)j << 8) + (t << 2)) = o.d2;
  float s = v.x * v.x + v.y * v.y + v.z * v.z + v.w * v.w;
#pragma unroll
  for (int off = 32; off >= 1; off >>= 1) s += __shfl_down(s, off);
  if (t == 0) cnorm[j] = s;
}

// ---------------- MFMA distance + per-tile top-2 -------------------------
// A = codebook (M=codes), B = z (N=rows): C[code][row]; acc seeded ||c||^2,
// cbb pre-scaled -2 -> acc = ||c||^2 - 2 z.c. 4-buffer counted-vmcnt
// pipeline (prefetch depth 3, one barrier per K-step, loads span barriers).
__global__ __launch_bounds__(256) void k_argmin_mfma(
    const unsigned short* __restrict__ zb,   // [16384][256] bf16
    const unsigned short* __restrict__ cbb,  // [8192][256]  bf16 of (-2*c)
    const float* __restrict__ cnorm,         // [8192] fp32
    f32x4* __restrict__ partials) {          // [16384][64] {b1,j1,b2,j2}
  __shared__ __align__(16) unsigned char lds[65536];  // 4 bufs x (8KB z + 8KB cb)

  const int tid = threadIdx.x;
  const int lane = tid & 63;
  const int w = tid >> 6;
  const int wc = w & 1;        // code half (64 codes)
  const int wr = w >> 1;       // row half  (64 rows)
  const int ct = blockIdx.x;
  const int r0 = blockIdx.y << 7;
  const int c0 = ct << 7;

  // staging: per tile t, thread loads 4x16B; LDS=[kq][row][16B] per buffer
  const int srow = tid & 127;
  const int skq = tid >> 7;
  const char* zg = (const char*)zb + (size_t)(r0 + srow) * 512 + skq * 16;
  const char* cg = (const char*)cbb + (size_t)(c0 + srow) * 512 + skq * 16;

  const int l4 = lane >> 4;
  const int lr = lane & 15;
  int aoff[4], boff[4];
#pragma unroll
  for (int i = 0; i < 4; ++i) {
    aoff[i] = l4 * 2048 + (wc * 64 + i * 16 + lr) * 16;  // codebook rows
    boff[i] = l4 * 2048 + (wr * 64 + i * 16 + lr) * 16;  // z rows
  }

  // seed acc with cnorm (code = c0 + wc*64 + mi*16 + l4*4 + reg)
  f32x4 acc[4][4];
  {
    const f32x4* cnv = (const f32x4*)(cnorm + c0 + wc * 64 + (l4 << 2));
#pragma unroll
    for (int mi = 0; mi < 4; ++mi) {
      f32x4 cn = cnv[mi * 4];
#pragma unroll
      for (int nj = 0; nj < 4; ++nj) acc[mi][nj] = cn;
    }
  }

#define STAGE(t, b)                                                        \
  {                                                                        \
    unsigned char* lz = lds + (b) * 16384 + tid * 16;                      \
    unsigned char* lc = lds + (b) * 16384 + 8192 + tid * 16;               \
    const char* zt = zg + (t) * 64;                                        \
    const char* ctp = cg + (t) * 64;                                       \
    gll16(zt, lz);      gll16(zt + 32, lz + 4096);                         \
    gll16(ctp, lc);     gll16(ctp + 32, lc + 4096);                        \
  }

  // prologue: stage tiles 0,1,2 (12 loads/thread outstanding)
  STAGE(0, 0); STAGE(1, 1); STAGE(2, 2);

#pragma unroll
  for (int ks = 0; ks < 8; ++ks) {
    // wait for tile ks's 4 loads (keep newer tiles in flight), then sync
    if (ks <= 5)      asm volatile("s_waitcnt vmcnt(8)" ::: "memory");
    else if (ks == 6) asm volatile("s_waitcnt vmcnt(4)" ::: "memory");
    else              asm volatile("s_waitcnt vmcnt(0)" ::: "memory");
    __builtin_amdgcn_s_barrier();
    __builtin_amdgcn_sched_barrier(0);
    // buf[(ks+3)&3] == buf[(ks-1)&3]: free (all waves' reads of it were
    // consumed by MFMAs before they arrived at this barrier)
    if (ks + 3 < 8) STAGE(ks + 3, (ks + 3) & 3);

    const unsigned char* bz = lds + (ks & 3) * 16384;
    const unsigned char* bc = bz + 8192;
    bf16x8 af[4], bfv[4];
#pragma unroll
    for (int i = 0; i < 4; ++i) af[i] = *(const bf16x8*)(bc + aoff[i]);
#pragma unroll
    for (int j = 0; j < 4; ++j) bfv[j] = *(const bf16x8*)(bz + boff[j]);
#pragma unroll
    for (int mi = 0; mi < 4; ++mi)
#pragma unroll
      for (int nj = 0; nj < 4; ++nj)
        acc[mi][nj] = __builtin_amdgcn_mfma_f32_16x16x32_bf16(af[mi], bfv[nj],
                                                              acc[mi][nj], 0, 0, 0);
  }
#undef STAGE

  // epilogue: in-lane top-2 over 16 codes per (row, nj), 2-step butterfly
  __syncthreads();                  // full drain; LDS reused as scratch
  f32x4* scr = (f32x4*)lds;         // [2 code-halves][128 rows]
  const int base_code = c0 + wc * 64 + (l4 << 2);

#pragma unroll
  for (int nj = 0; nj < 4; ++nj) {
    float b1 = 3.4e38f, b2 = 3.4e38f;
    int q1 = 0, q2 = 0;
#pragma unroll
    for (int mi = 0; mi < 4; ++mi)
#pragma unroll
      for (int rg = 0; rg < 4; ++rg) {
        float d = acc[mi][nj][rg];
        int q = mi * 4 + rg;
        bool u1 = d < b1;
        bool u2 = d < b2;
        float nb2 = u1 ? b1 : (u2 ? d : b2);
        int nq2 = u1 ? q1 : (u2 ? q : q2);
        b1 = u1 ? d : b1;
        q1 = u1 ? q : q1;
        b2 = nb2; q2 = nq2;
      }
    int j1 = base_code + ((q1 >> 2) << 4) + (q1 & 3);
    int j2 = base_code + ((q2 >> 2) << 4) + (q2 & 3);
#pragma unroll
    for (int m = 16; m <= 32; m <<= 1) {
      float e1 = __shfl_xor(b1, m); int i1 = __shfl_xor(j1, m);
      float e2 = __shfl_xor(b2, m); int i2 = __shfl_xor(j2, m);
      MERGE2(e1, i1, e2, i2);
    }
    if (l4 == 0) {
      f32x4 e;
      e[0] = b1; e[1] = __int_as_float(j1);
      e[2] = b2; e[3] = __int_as_float(j2);
      scr[wc * 128 + wr * 64 + nj * 16 + lr] = e;
    }
  }
  __syncthreads();
  if (tid < 128) {
    f32x4 e0 = scr[tid], e1v = scr[128 + tid];
    float b1 = e0[0], b2 = e0[2];
    int j1 = __float_as_int(e0[1]), j2 = __float_as_int(e0[3]);
    float e1 = e1v[0], e2 = e1v[2];
    int i1 = __float_as_int(e1v[1]), i2 = __float_as_int(e1v[3]);
    MERGE2(e1, i1, e2, i2);
    f32x4 e;
    e[0] = b1; e[1] = __int_as_float(j1);
    e[2] = b2; e[3] = __int_as_float(j2);
    partials[(size_t)(r0 + tid) * 64 + ct] = e;  // transposed: [row][ct]
  }
}

// -------- merge partials + exact refine (wave/row) + fused histogram ------
__global__ __launch_bounds__(256) void k_reduce(
    const f32x4* __restrict__ partials, const float* __restrict__ z,
    const float* __restrict__ cb, float* __restrict__ out_codes,
    int* __restrict__ cnt) {
  const int row = blockIdx.x * 4 + (threadIdx.x >> 6);
  const int lane = threadIdx.x & 63;

  f32x4 e = partials[(size_t)row * 64 + lane];
  const float ob1 = e[0], ob2 = e[2];
  const int oj1 = __float_as_int(e[1]), oj2 = __float_as_int(e[3]);

  float b1 = ob1, b2 = ob2;
  int j1 = oj1, j2 = oj2;
#pragma unroll
  for (int m = 1; m <= 32; m <<= 1) {
    float c1 = __shfl_xor(b1, m); int i1 = __shfl_xor(j1, m);
    float c2 = __shfl_xor(b2, m); int i2 = __shfl_xor(j2, m);
    MERGE2(c1, i1, c2, i2);
  }
  int chosen = j1;

  if (b2 - b1 < 0.5f) {   // wave-uniform near-tie: exact fp64 re-eval
    const float win = b1 + 0.5f;
    const float* zr = z + ((size_t)row << 8);
    double bestd = 1e300; int bestj = 0x7fffffff;
#pragma unroll
    for (int h = 0; h < 2; ++h) {
      float bv = h ? ob2 : ob1;
      int jv = h ? oj2 : oj1;
      if (bv <= win && jv != 0x7fffffff) {
        const float* c = cb + ((size_t)jv << 8);
        double d = 0.0;
        for (int k = 0; k < DIM; ++k) {
          double df = (double)zr[k] - (double)c[k];
          d += df * df;
        }
        if (d < bestd || (d == bestd && jv < bestj)) { bestd = d; bestj = jv; }
      }
    }
#pragma unroll
    for (int m = 1; m <= 32; m <<= 1) {
      double od = __shfl_xor(bestd, m);
      int oj = __shfl_xor(bestj, m);
      if (od < bestd || (od == bestd && oj < bestj)) { bestd = od; bestj = oj; }
    }
    chosen = bestj;
  }
  if (lane == 0) {
    out_codes[row] = (float)chosen;
    if (cnt) atomicAdd(&cnt[chosen], 1);
  }
}

// ---------------- counting-sort EMA path ----------------------------------
__global__ __launch_bounds__(1024) void k_scan(
    const int* __restrict__ cnt, int* __restrict__ start,
    int* __restrict__ cursor, const float* __restrict__ ema_cs,
    float* __restrict__ cs_out) {
  __shared__ int ssum[1024];
  const int t = threadIdx.x;
  const int base = t * 8;
  int c[8], s = 0;
#pragma unroll
  for (int i = 0; i < 8; ++i) { c[i] = cnt[base + i]; s += c[i]; }
  ssum[t] = s;
  __syncthreads();
  for (int off = 1; off < 1024; off <<= 1) {
    int v = 0;
    if (t >= off) v = ssum[t - off];
    __syncthreads();
    ssum[t] += v;
    __syncthreads();
  }
  int ex = ssum[t] - s;  // exclusive base
#pragma unroll
  for (int i = 0; i < 8; ++i) {
    start[base + i] = ex;
    cursor[base + i] = ex;
    cs_out[base + i] = 0.99f * ema_cs[base + i] + 0.01f * (float)c[i];
    ex += c[i];
  }
}

__global__ __launch_bounds__(256) void k_place(const float* __restrict__ codesf,
                                               int* __restrict__ cursor,
                                               int* __restrict__ rowlist) {
  int i = blockIdx.x * 256 + threadIdx.x;
  int c = (int)codesf[i];
  int p = atomicAdd(&cursor[c], 1);
  rowlist[p] = i;
}

// fused per-code pass: z_q gather-write + dw sum + EMA + codebook + loss
__global__ __launch_bounds__(256) void k_dw2(
    const float* __restrict__ z, const float* __restrict__ cb,
    const int* __restrict__ start, const int* __restrict__ cnt,
    const int* __restrict__ rowlist, const float* __restrict__ ema_w,
    const float* __restrict__ cs_new, float* __restrict__ zq,
    float* __restrict__ ew, float* __restrict__ cb_out,
    float* __restrict__ loss_part) {
  const int k = blockIdx.x;
  const int d = threadIdx.x;
  const int s = start[k], n = cnt[k];
  const size_t o = ((size_t)k << 8) + d;
  const float q = cb[o];
  float a = 0.0f, lacc = 0.0f;
  for (int t = 0; t < n; ++t) {
    const size_t ro = ((size_t)rowlist[s + t] << 8) + d;
    const float zv = z[ro];
    a += zv;
    zq[ro] = q;                      // z_q_st value == old codebook row
    const float df = zv - q;
    lacc += df * df;
  }
  const float v = 0.99f * ema_w[o] + 0.01f * a;
  ew[o] = v;
  cb_out[o] = v / (cs_new[k] + 1e-5f);

#pragma unroll
  for (int off = 32; off >= 1; off >>= 1) lacc += __shfl_down(lacc, off);
  __shared__ float wp[4];
  if ((d & 63) == 0) wp[d >> 6] = lacc;
  __syncthreads();
  if (d == 0 && n > 0) {
    float ssum = (wp[0] + wp[1]) + (wp[2] + wp[3]);
    atomicAdd(loss_part + (k & 255), ssum * (float)(0.1 / 4194304.0));
  }
}

__global__ __launch_bounds__(256) void k_loss_final(
    const float* __restrict__ part, float* __restrict__ loss) {
  float s = part[threadIdx.x];
#pragma unroll
  for (int off = 32; off >= 1; off >>= 1) s += __shfl_down(s, off);
  __shared__ float w[4];
  if ((threadIdx.x & 63) == 0) w[threadIdx.x >> 6] = s;
  __syncthreads();
  if (threadIdx.x == 0) loss[0] = (w[0] + w[1]) + (w[2] + w[3]);
}

// ---------------- fallback atomic path (ws too small) ---------------------
__global__ __launch_bounds__(256) void k_scatter(
    const float* __restrict__ z, const float* __restrict__ cb,
    const float* __restrict__ codesf, float* __restrict__ zq,
    float* __restrict__ loss, float* __restrict__ cs_acc,
    float* __restrict__ ew_acc) {
  const int row = blockIdx.x;
  const int d = threadIdx.x;
  const int c = (int)codesf[row];
  const float zv = z[((size_t)row << 8) + d];
  const float qv = cb[((size_t)c << 8) + d];
  zq[((size_t)row << 8) + d] = zv + (qv - zv);
  float diff = zv - qv;
  float sq = diff * diff;
#pragma unroll
  for (int off = 32; off >= 1; off >>= 1) sq += __shfl_down(sq, off);
  __shared__ float wpart[4];
  if ((d & 63) == 0) wpart[d >> 6] = sq;
  __syncthreads();
  if (d == 0) {
    float s = (wpart[0] + wpart[1]) + (wpart[2] + wpart[3]);
    atomicAdd(loss, s * (float)(0.1 / 4194304.0));
    atomicAdd(cs_acc + c, 1.0f);
  }
  atomicAdd(ew_acc + ((size_t)c << 8) + d, zv);
}

__global__ __launch_bounds__(256) void k_ema_cs(const float* __restrict__ ema_cs,
                                                float* __restrict__ cs_io) {
  const int k = blockIdx.x * 256 + threadIdx.x;
  const float cnt = cs_io[k];
  cs_io[k] = 0.99f * ema_cs[k] + 0.01f * cnt;
}

__global__ __launch_bounds__(256) void k_ema_w(const float* __restrict__ ema_w,
                                               const float* __restrict__ cs_new,
                                               float* __restrict__ ew_io,
                                               float* __restrict__ cb_out) {
  const int i = blockIdx.x * 256 + threadIdx.x;
  const float dw = ew_io[i];
  const float v = 0.99f * ema_w[i] + 0.01f * dw;
  ew_io[i] = v;
  cb_out[i] = v / (cs_new[i >> 8] + 1e-5f);
}

// ---------------- launch --------------------------------------------------
extern "C" void kernel_launch(void* const* d_in, const int* in_sizes, int n_in,
                              void* d_out, int out_size, void* d_ws, size_t ws_size,
                              hipStream_t stream) {
  const float* z      = (const float*)d_in[0];
  const float* cb     = (const float*)d_in[1];
  const float* ema_cs = (const float*)d_in[2];
  const float* ema_w  = (const float*)d_in[3];
  float* out = (float*)d_out;

  float* o_zq    = out + OFF_ZQ;
  float* o_codes = out + OFF_CODES;
  float* o_loss  = out + OFF_LOSS;
  float* o_cb    = out + OFF_CB;
  float* o_cs    = out + OFF_CS;
  float* o_ew    = out + OFF_EW;

  // scratch aliases inside output regions (each overwritten later in order):
  //   z_bf16 (8.39MB)                 -> o_cb region (k_dw2 cb_out overwrites)
  //   cb_bf16 (4.19MB) + cnorm (32KB) -> o_ew region (k_dw2 ew overwrites)
  //   partials (16.78MB exact)        -> o_zq region (k_dw2 zq overwrites)
  uintptr_t zb_a  = ((uintptr_t)o_cb + 15) & ~(uintptr_t)15;
  uintptr_t cbb_a = ((uintptr_t)o_ew + 15) & ~(uintptr_t)15;
  unsigned short* zbuf  = (unsigned short*)zb_a;
  unsigned short* cbbuf = (unsigned short*)cbb_a;
  float* cnorm = (float*)(cbb_a + 4194304);
  f32x4* partials = (f32x4*)o_zq;

  const size_t ws_need = 4 * (8192 * 3 + 16384 + 256);  // 164864 B
  const bool sorted = (ws_size >= ws_need);
  int* cnt      = (int*)d_ws;
  int* start    = cnt + 8192;
  int* cursor   = start + 8192;
  int* rowlist  = cursor + 8192;
  float* loss_part = (float*)(rowlist + 16384);

  if (sorted) (void)hipMemsetAsync(d_ws, 0, ws_need, stream);

  k_cvt <<<2048, 256, 0, stream>>>(z, zbuf, 524288);
  k_prep<<<2048, 256, 0, stream>>>(cb, cbbuf, cnorm);

  dim3 g(64, 128);
  k_argmin_mfma<<<g, 256, 0, stream>>>(zbuf, cbbuf, cnorm, partials);
  k_reduce<<<N_ROWS / 4, 256, 0, stream>>>(partials, z, cb, o_codes,
                                           sorted ? cnt : (int*)nullptr);

  if (sorted) {
    k_scan <<<1, 1024, 0, stream>>>(cnt, start, cursor, ema_cs, o_cs);
    k_place<<<64, 256, 0, stream>>>(o_codes, cursor, rowlist);
    k_dw2<<<KCODES, 256, 0, stream>>>(z, cb, start, cnt, rowlist, ema_w,
                                      o_cs, o_zq, o_ew, o_cb, loss_part);
    k_loss_final<<<1, 256, 0, stream>>>(loss_part, o_loss);
  } else {
    (void)hipMemsetAsync(o_loss, 0,
                         (size_t)(OUT_TOTAL - OFF_LOSS) * sizeof(float), stream);
    k_scatter<<<N_ROWS, 256, 0, stream>>>(z, cb, o_codes, o_zq, o_loss, o_cs,
                                          o_ew);
    k_ema_cs<<<KCODES / 256, 256, 0, stream>>>(ema_cs, o_cs);
    k_ema_w <<<KCODES * DIM / 256, 256, 0, stream>>>(ema_w, o_cs, o_ew, o_cb);
  }
}